// Round 22
// baseline (193.797 us; speedup 1.0000x reference)
//
#include <hip/hip_runtime.h>
#include <stdint.h>

#define N2   8192
#define N    4096
#define LOGN 12
#define F_TOT 4097   // N2/2 + 1
#define FP    4112   // padded f-stride (float2), 16-aligned
#define D    128
#define K    16
#define B    2
#define PI_F 3.14159265358979323846f
#define NPAD (N + (N >> 5))   // padded LDS float count

typedef _Float16 f16x8 __attribute__((ext_vector_type(8)));
typedef float    f32x4 __attribute__((ext_vector_type(4)));
typedef float    f32x2v __attribute__((ext_vector_type(2)));

// Padded LDS index: spreads power-of-2 strides across banks (<=3-way all passes).
__device__ __forceinline__ int pad(int w) { return w + (w >> 5); }

__device__ __forceinline__ _Float16 hpick(uint32_t w, int hi) {
  union { unsigned short u; _Float16 h; } c;
  c.u = (unsigned short)(hi ? (w >> 16) : (w & 0xffffu));
  return c.h;
}

__device__ __forceinline__ uint32_t packh2(float a, float b) {
  union { uint32_t u; unsigned short s[2]; } p;
  union { unsigned short u; _Float16 h; } ca, cb;
  ca.h = (_Float16)a; cb.h = (_Float16)b;
  p.s[0] = ca.u; p.s[1] = cb.u;
  return p.u;
}

// non-temporal float2 load via ext_vector (HIP_vector_type not accepted)
__device__ __forceinline__ float2 ntload2(const float2* p) {
  f32x2v v = __builtin_nontemporal_load((const f32x2v*)p);
  return make_float2(v.x, v.y);
}

// tw[len+j] = (cos, sin)(pi*j/len), len = 1..2048 power of two, j < len.
__device__ __forceinline__ void fill_tw(float2* tw, int tid, int nthr) {
  for (int i = tid + 1; i < N; i += nthr) {
    int s = 31 - __clz(i);
    int j = i - (1 << s);
    float ang = PI_F * (float)j / (float)(1 << s);
    float wi_, wr_; __sincosf(ang, &wi_, &wr_);
    tw[i] = make_float2(wr_, wi_);
  }
}

// In-place DIT FFT on bit-reverse-loaded (pad-indexed) data: 6 fused
// two-stage passes (radix-4 work per group). sign=-1 fwd, +1 inv.
__device__ __forceinline__ void fft_lds(float* re, float* im, const float2* tw,
                                        int tid, int nthr, float sign) {
  for (int s = 0; s < LOGN; s += 2) {
    const int len = 1 << s;
    for (int t = tid; t < (N >> 2); t += nthr) {
      const int j = t & (len - 1);
      const int base = ((t >> s) << (s + 2)) + j;
      const int i0 = pad(base), i1 = pad(base + len);
      const int i2 = pad(base + 2 * len), i3 = pad(base + 3 * len);
      float2 w1 = tw[len + j];
      float2 w2 = tw[2 * len + j];
      float2 w3 = tw[3 * len + j];     // = tw[2*len + (j+len)]
      const float w1r = w1.x, w1i = sign * w1.y;
      const float w2r = w2.x, w2i = sign * w2.y;
      const float w3r = w3.x, w3i = sign * w3.y;
      float x0r = re[i0], x0i = im[i0];
      float x1r = re[i1], x1i = im[i1];
      float x2r = re[i2], x2i = im[i2];
      float x3r = re[i3], x3i = im[i3];
      float t1r = w1r * x1r - w1i * x1i, t1i = w1r * x1i + w1i * x1r;
      float t3r = w1r * x3r - w1i * x3i, t3i = w1r * x3i + w1i * x3r;
      float b0r = x0r + t1r, b0i = x0i + t1i;
      float b1r = x0r - t1r, b1i = x0i - t1i;
      float b2r = x2r + t3r, b2i = x2i + t3i;
      float b3r = x2r - t3r, b3i = x2i - t3i;
      float u2r = w2r * b2r - w2i * b2i, u2i = w2r * b2i + w2i * b2r;
      float u3r = w3r * b3r - w3i * b3i, u3i = w3r * b3i + w3i * b3r;
      re[i0] = b0r + u2r; im[i0] = b0i + u2i;
      re[i2] = b0r - u2r; im[i2] = b0i - u2i;
      re[i1] = b1r + u3r; im[i1] = b1i + u3i;
      re[i3] = b1r - u3r; im[i3] = b1i - u3i;
    }
    __syncthreads();
  }
}

// x (B,L,D) -> xT (B,D,L) so fwd_fft loads are coalesced.
__global__ __launch_bounds__(256) void transpose_x(const float* __restrict__ x,
                                                   float* __restrict__ xT) {
  __shared__ float t[32][33];
  const int b = blockIdx.z;
  const int l0 = blockIdx.x * 32, d0 = blockIdx.y * 32;
  const int c = threadIdx.x & 31, r0 = threadIdx.x >> 5;
#pragma unroll
  for (int i = 0; i < 4; ++i) {
    int r = r0 + i * 8;
    t[r][c] = x[((size_t)b * N + l0 + r) * D + d0 + c];
  }
  __syncthreads();
#pragma unroll
  for (int i = 0; i < 4; ++i) {
    int r = r0 + i * 8;
    xT[((size_t)b * D + d0 + r) * N + l0 + c] = t[c][r];
  }
}

// outT (B,D,N) -> out (B,L,D). Final output: non-temporal stores.
__global__ __launch_bounds__(256) void transpose_out(const float* __restrict__ outT,
                                                     float* __restrict__ out) {
  __shared__ float t[32][33];
  const int b = blockIdx.z;
  const int l0 = blockIdx.x * 32, d0 = blockIdx.y * 32;
  const int c = threadIdx.x & 31, r0 = threadIdx.x >> 5;
#pragma unroll
  for (int i = 0; i < 4; ++i) {
    int r = r0 + i * 8;
    t[r][c] = outT[((size_t)b * D + d0 + r) * N + l0 + c];
  }
  __syncthreads();
#pragma unroll
  for (int i = 0; i < 4; ++i) {
    int r = r0 + i * 8;
    __builtin_nontemporal_store(t[c][r], &out[((size_t)b * N + l0 + r) * D + d0 + c]);
  }
}

// Forward rfft(n=8192) of real length-4096 signals via 4096-pt complex FFT.
// 1024 threads (4 waves/SIMD). Layouts: Ufh[b][f][d] (half2), Vf[f][k].
// Blocks 0..255: x (b,d). 256..271: filters (k).
// 272..303: M->f16 re-layout Mt[pm][eq4][k][kd8:16][el:32][8].
__global__ __launch_bounds__(1024) void fwd_fft(const float* __restrict__ xT,
                                                const float* __restrict__ filt,
                                                const float* __restrict__ Mp,
                                                const float* __restrict__ Mm,
                                                uint32_t* __restrict__ Ufh,
                                                float2* __restrict__ Vf,
                                                _Float16* __restrict__ Mt) {
  __shared__ float re[NPAD];
  __shared__ float im[NPAD];
  __shared__ float2 tw[N];
  const int tid = threadIdx.x;
  const int sig = blockIdx.x;

  if (sig >= B * D + K) {          // ---- M prep path ----
    const int pid = sig - (B * D + K);
    const int k = pid & 15, h = pid >> 4;
    const float* src = (h ? Mm : Mp) + (size_t)k * D * D;
    for (int d0 = 0; d0 < D; d0 += 16) {
      for (int i = tid; i < 16 * D; i += 1024) re[i] = src[(size_t)d0 * D + i];
      __syncthreads();
      if (tid < 256) {
        const int e = tid >> 1, c0 = (tid & 1) * 8;
        f16x8 w;
#pragma unroll
        for (int j = 0; j < 8; ++j) w[j] = (_Float16)re[(c0 + j) * D + e];
        const int eq = e >> 5, el = e & 31;
        const size_t kd8 = (size_t)(d0 + c0) >> 3;
        *(f16x8*)(Mt + (((((size_t)h * 4 + eq) * K + k) * 16 + kd8) * 32 + el) * 8) = w;
      }
      __syncthreads();
    }
    return;
  }

  fill_tw(tw, tid, 1024);

  const float* in; int istride;
  int b = 0, d = 0, k = 0;
  const bool isx = sig < B * D;
  if (isx) { b = sig >> 7; d = sig & (D - 1); in = xT + ((size_t)b * D + d) * N; istride = 1; }
  else     { k = sig - B * D; in = filt + k; istride = K; }

  for (int m = tid; m < N; m += 1024) {
    float vr = 0.f, vi = 0.f;
    if (m < (N >> 1)) {
      if (istride == 1) { float2 z = ((const float2*)in)[m]; vr = z.x; vi = z.y; }
      else { vr = in[(size_t)(2 * m) * istride]; vi = in[(size_t)(2 * m + 1) * istride]; }
    }
    int dst = pad(__brev(m) >> (32 - LOGN));
    re[dst] = vr; im[dst] = vi;
  }
  __syncthreads();
  fft_lds(re, im, tw, tid, 1024, -1.0f);

  // recombine in (f, N-f) pairs sharing one sincos
  for (int f = tid; f <= (N >> 1); f += 1024) {
    int f2 = f & (N - 1), fn = (N - f) & (N - 1);
    float zr = re[pad(f2)], zi = im[pad(f2)];
    float nr = re[pad(fn)], ni = im[pad(fn)];
    float Er = 0.5f * (zr + nr), Ei = 0.5f * (zi - ni);
    float Or = 0.5f * (zi + ni), Oi = -0.5f * (zr - nr);
    float ang = -PI_F * (float)f / (float)N;
    float wi_, wr_; __sincosf(ang, &wi_, &wr_);
    float X0r = Er + wr_ * Or - wi_ * Oi;
    float X0i = Ei + wr_ * Oi + wi_ * Or;
    float X1r = Er - wr_ * Or + wi_ * Oi;
    float X1i = -Ei + wr_ * Oi + wi_ * Or;
    if (isx) {
      uint32_t* o = Ufh + ((size_t)b * F_TOT) * D + d;
      o[(size_t)f * D]       = packh2(X0r, X0i);
      o[(size_t)(N - f) * D] = packh2(X1r, X1i);
    } else {
      Vf[(size_t)f * K + k]       = make_float2(X0r, X0i);
      Vf[(size_t)(N - f) * K + k] = make_float2(X1r, X1i);
    }
  }
}

// MFMA middle — barrier-free direct-L2 B reads WITH EXPLICIT REGISTER
// DOUBLE-BUFFERED PREFETCH (T14): fully-unrolled 32-step loop (16k x 2pm);
// step t issues the 4 B-fragment loads for t+1 into the other buffer
// (static t&1 indexing), so the ~300cyc L2 latency hides under step t's
// MFMA+fixup. R19/R21 showed the plain loop never prefetches (VGPR=84 =
// A only) and is serialization-bound at ~40us regardless of grid size.
// Single Gt slab, grid 544, XCD co-location swizzle. launch_bounds(256,3)
// (VGPR cap ~170; (256,4)'s 64-cap spills — R12/R20).
__global__ __launch_bounds__(256, 3) void middle_mfma(const uint32_t* __restrict__ Ufh,
                                                      const float2* __restrict__ Vf,
                                                      const _Float16* __restrict__ Mt,
                                                      float2* __restrict__ Gt) {
  __shared__ __align__(16) char smem[16896];   // Vl (8 KB) ... aliased tr [64][33]
  float2* Vl = (float2*)smem;                  // [pm2][fl32][k16] = 8 KB

  // ---- XCD co-location decode: xcd = id%8 (heuristic), fx8 ≡ id (mod 8)
  const int lin = blockIdx.x;
  const int r8 = lin & 7, m = lin >> 3;        // m in [0,68)
  const int fx8 = (m >> 2) * 8 + r8;           // f-tile index, ≡ r8 (mod 8)
  const int eq  = m & 3;
  if (fx8 > 128) return;
  const int fx = fx8 * 32;

  const int tid = threadIdx.x;
  const int l = tid & 63, w = tid >> 6;
  const int l15 = l & 15, g = l >> 4;
  const int fg = w >> 1, eg = w & 1;
  const int fo = l15 >> 2, bb = (l15 >> 1) & 1, ri = l15 & 1;

  // ---- V into LDS: Vl[pm][fl][k], all 16 k (Vf is [f][k])
  {
    const int fl = tid >> 3, kq = tid & 7;
    int fe = fx + fl; if (fe > N) fe = N;
    *(float4*)&Vl[((size_t)0 * 32 + fl) * 16 + kq * 2] =
        *(const float4*)&Vf[(size_t)fe * K + kq * 2];
    *(float4*)&Vl[((size_t)1 * 32 + fl) * 16 + kq * 2] =
        *(const float4*)&Vf[(size_t)(N - fe) * K + kq * 2];
  }

  // ---- k-invariant A fragments: A[s][ds], a[j] = U[b, f, d=ds*32+g*8+j].(ri)
  f16x8 A[4][4];
#pragma unroll
  for (int s = 0; s < 4; ++s) {
    int f = fx + fg * 16 + s * 4 + fo; if (f > N) f = N;
    const uint4* ur = (const uint4*)(Ufh + ((size_t)bb * F_TOT + f) * D);
#pragma unroll
    for (int ds = 0; ds < 4; ++ds) {
      uint4 w0 = ur[ds * 8 + g * 2];
      uint4 w1 = ur[ds * 8 + g * 2 + 1];
      f16x8 a;
      a[0] = hpick(w0.x, ri); a[1] = hpick(w0.y, ri);
      a[2] = hpick(w0.z, ri); a[3] = hpick(w0.w, ri);
      a[4] = hpick(w1.x, ri); a[5] = hpick(w1.y, ri);
      a[6] = hpick(w1.z, ri); a[7] = hpick(w1.w, ri);
      A[s][ds] = a;
    }
  }

  f32x4 acc[4];
#pragma unroll
  for (int s = 0; s < 4; ++s) acc[s] = (f32x4)0.f;

  __syncthreads();   // Vl visible; the ONLY pre-epilogue barrier

  const int boff = (eg * 16 + l15) * 8;

  // ---- register double-buffered B prefetch over 32 (k,pm) steps
  f16x8 Bf0[4], Bf1[4];
  {
    const _Float16* mb0 = Mt + ((size_t)eq * K + 0) * 4096;   // t=0: pm=0, kg=0
#pragma unroll
    for (int ds = 0; ds < 4; ++ds)
      Bf0[ds] = *(const f16x8*)(mb0 + (size_t)(ds * 4 + g) * 256 + boff);
  }

#pragma unroll
  for (int t = 0; t < 32; ++t) {
    const int kg = t >> 1, pm = t & 1;

    if (t + 1 < 32) {
      const int kn = (t + 1) >> 1, pn = (t + 1) & 1;
      const _Float16* mbn = Mt + (((size_t)pn * 4 + eq) * K + kn) * 4096;
#pragma unroll
      for (int ds = 0; ds < 4; ++ds) {
        f16x8 v = *(const f16x8*)(mbn + (size_t)(ds * 4 + g) * 256 + boff);
        if (t & 1) Bf0[ds] = v; else Bf1[ds] = v;
      }
    }

    float2 vv[4];
#pragma unroll
    for (int s = 0; s < 4; ++s)
      vv[s] = Vl[((size_t)pm * 32 + fg * 16 + s * 4 + g) * 16 + kg];

    f32x4 P[4];
#pragma unroll
    for (int ds = 0; ds < 4; ++ds) {
      f16x8 bf = (t & 1) ? Bf1[ds] : Bf0[ds];
#pragma unroll
      for (int s = 0; s < 4; ++s) {
        f32x4 cin = (ds == 0) ? (f32x4)0.f : P[s];
        P[s] = __builtin_amdgcn_mfma_f32_16x16x32_f16(A[s][ds], bf, cin, 0, 0, 0);
      }
    }
#pragma unroll
    for (int s = 0; s < 4; ++s) {
      const float vr = vv[s].x, vy = vv[s].y;
      if (pm == 0) {   // G += (vr + i vy) * (PR + i PI)
        acc[s][0] += vr * P[s][0] - vy * P[s][1];
        acc[s][1] += vy * P[s][0] + vr * P[s][1];
        acc[s][2] += vr * P[s][2] - vy * P[s][3];
        acc[s][3] += vy * P[s][2] + vr * P[s][3];
      } else {         // G += conj(vr + i vy) * (PR + i PI)
        acc[s][0] += vr * P[s][0] + vy * P[s][1];
        acc[s][1] += vr * P[s][1] - vy * P[s][0];
        acc[s][2] += vr * P[s][2] + vy * P[s][3];
        acc[s][3] += vr * P[s][3] - vy * P[s][2];
      }
    }
  }

  __syncthreads();   // all Vl reads done before tr aliases smem

  // ---- epilogue: LDS transpose (aliases smem) -> coalesced NT float4 stores
  float2* tr = (float2*)smem;   // [64][33]
#pragma unroll
  for (int s = 0; s < 4; ++s) {
    const int fl = fg * 16 + s * 4 + g;
    const int el = eg * 16 + l15;
    tr[(size_t)el * 33 + fl]        = make_float2(acc[s][0], acc[s][1]);
    tr[(size_t)(32 + el) * 33 + fl] = make_float2(acc[s][2], acc[s][3]);
  }
  __syncthreads();
#pragma unroll
  for (int p = 0; p < 4; ++p) {
    const int row = p * 16 + (tid >> 4);        // row = bo*32 + e_local
    const int bo = row >> 5, e_gl = eq * 32 + (row & 31);
    const int c = (tid & 15) * 2;
    const int fgl = fx + c;
    if (fgl < F_TOT) {
      float2 v0 = tr[(size_t)row * 33 + c], v1 = tr[(size_t)row * 33 + c + 1];
      f32x4 v = {v0.x, v0.y, v1.x, v1.y};
      __builtin_nontemporal_store(v, (f32x4*)&Gt[((size_t)bo * D + e_gl) * FP + fgl]);
    }
  }
}

// irfft(n=8192) per (b,e): NON-TEMPORAL coalesced row reads of the single
// Gt slab, (kk, N-kk) pairs share one twiddle, fused-pass FFT, coalesced
// outT writes. 1024 threads.
__global__ __launch_bounds__(1024) void inv_fft(const float2* __restrict__ Gt,
                                                float* __restrict__ outT) {
  __shared__ float re[NPAD];
  __shared__ float im[NPAD];
  __shared__ float2 tw[N];
  const int tid = threadIdx.x;
  const int sig = blockIdx.x;
  const int b = sig >> 7, e = sig & (D - 1);
  const float2* g0 = Gt + ((size_t)b * D + e) * FP;

  fill_tw(tw, tid, 1024);

  for (int kk = tid; kk <= (N >> 1); kk += 1024) {
    float2 Xk = ntload2(&g0[kk]);
    float2 Xn = ntload2(&g0[N - kk]);
    float Er = 0.5f * (Xk.x + Xn.x), Ei = 0.5f * (Xk.y - Xn.y);
    float Dr = 0.5f * (Xk.x - Xn.x), Di = 0.5f * (Xk.y + Xn.y);
    float ang = PI_F * (float)kk / (float)N;
    float wi_, wr_; __sincosf(ang, &wi_, &wr_);
    float Or = Dr * wr_ - Di * wi_;
    float Oi = Dr * wi_ + Di * wr_;
    int d1 = pad(__brev(kk) >> (32 - LOGN));
    re[d1] = Er - Oi; im[d1] = Ei + Or;
    if (kk != 0 && kk != (N >> 1)) {
      int d2 = pad(__brev(N - kk) >> (32 - LOGN));
      re[d2] = Er + Oi; im[d2] = -Ei + Or;   // conj-pair: same twiddle
    }
  }
  __syncthreads();
  fft_lds(re, im, tw, tid, 1024, +1.0f);
  const float scale = 1.0f / (float)N;
  float2* ob = (float2*)(outT + ((size_t)b * D + e) * N);
  for (int m = tid; m < (N >> 1); m += 1024) {
    int i0 = pad(m);
    ob[m] = make_float2(re[i0] * scale, im[i0] * scale);
  }
}

extern "C" void kernel_launch(void* const* d_in, const int* in_sizes, int n_in,
                              void* d_out, int out_size, void* d_ws, size_t ws_size,
                              hipStream_t stream) {
  const float* x  = (const float*)d_in[0];
  const float* fl = (const float*)d_in[1];
  const float* Mp = (const float*)d_in[2];
  const float* Mm = (const float*)d_in[3];
  float* out = (float*)d_out;

  float*    xT  = (float*)d_ws;                               // B*D*N f32 (4 MB), reused as outT
  uint32_t* Ufh = (uint32_t*)(xT + (size_t)B * D * N);        // B*F_TOT*D half2 ([b][f][d])
  float2*   Vf  = (float2*)(Ufh + (size_t)B * F_TOT * D);     // F_TOT*K ([f][k])
  float2*   Gt  = Vf + (size_t)F_TOT * K;                     // single slab B*D*FP
  _Float16* Mt  = (_Float16*)(Gt + (size_t)B * D * FP);       // 1 MB f16

  transpose_x<<<dim3(N / 32, D / 32, B), 256, 0, stream>>>(x, xT);
  fwd_fft<<<B * D + K + 32, 1024, 0, stream>>>(xT, fl, Mp, Mm, Ufh, Vf, Mt);
  middle_mfma<<<544, 256, 0, stream>>>(Ufh, Vf, Mt, Gt);
  inv_fft<<<B * D, 1024, 0, stream>>>(Gt, xT);   // xT reused as outT (B,D,N)
  transpose_out<<<dim3(N / 32, D / 32, B), 256, 0, stream>>>(xT, out);
}

// Round 23
// 69.232 us; speedup vs baseline: 2.7993x; 2.7993x over previous
//
#include <hip/hip_runtime.h>
#include <stdint.h>

#define N2   8192
#define N    4096
#define LOGN 12
#define F_TOT 4097   // N2/2 + 1
#define FP    4112   // padded f-stride (float2), 16-aligned
#define D    128
#define K    16
#define B    2
#define PI_F 3.14159265358979323846f
#define NPAD (N + (N >> 5))   // padded LDS float count

typedef _Float16 f16x8 __attribute__((ext_vector_type(8)));
typedef float    f32x4 __attribute__((ext_vector_type(4)));
typedef float    f32x2v __attribute__((ext_vector_type(2)));

__device__ __forceinline__ void gload_lds16(const void* g, void* l) {
  __builtin_amdgcn_global_load_lds((const __attribute__((address_space(1))) uint32_t*)g,
                                   (__attribute__((address_space(3))) uint32_t*)l, 16, 0, 0);
}

// Padded LDS index: spreads power-of-2 strides across banks (<=3-way all passes).
__device__ __forceinline__ int pad(int w) { return w + (w >> 5); }

__device__ __forceinline__ _Float16 hpick(uint32_t w, int hi) {
  union { unsigned short u; _Float16 h; } c;
  c.u = (unsigned short)(hi ? (w >> 16) : (w & 0xffffu));
  return c.h;
}

__device__ __forceinline__ uint32_t packh2(float a, float b) {
  union { uint32_t u; unsigned short s[2]; } p;
  union { unsigned short u; _Float16 h; } ca, cb;
  ca.h = (_Float16)a; cb.h = (_Float16)b;
  p.s[0] = ca.u; p.s[1] = cb.u;
  return p.u;
}

// non-temporal float2 load via ext_vector (HIP_vector_type not accepted)
__device__ __forceinline__ float2 ntload2(const float2* p) {
  f32x2v v = __builtin_nontemporal_load((const f32x2v*)p);
  return make_float2(v.x, v.y);
}

// tw[len+j] = (cos, sin)(pi*j/len), len = 1..2048 power of two, j < len.
__device__ __forceinline__ void fill_tw(float2* tw, int tid, int nthr) {
  for (int i = tid + 1; i < N; i += nthr) {
    int s = 31 - __clz(i);
    int j = i - (1 << s);
    float ang = PI_F * (float)j / (float)(1 << s);
    float wi_, wr_; __sincosf(ang, &wi_, &wr_);
    tw[i] = make_float2(wr_, wi_);
  }
}

// In-place DIT FFT on bit-reverse-loaded (pad-indexed) data: 6 fused
// two-stage passes (radix-4 work per group). sign=-1 fwd, +1 inv.
__device__ __forceinline__ void fft_lds(float* re, float* im, const float2* tw,
                                        int tid, int nthr, float sign) {
  for (int s = 0; s < LOGN; s += 2) {
    const int len = 1 << s;
    for (int t = tid; t < (N >> 2); t += nthr) {
      const int j = t & (len - 1);
      const int base = ((t >> s) << (s + 2)) + j;
      const int i0 = pad(base), i1 = pad(base + len);
      const int i2 = pad(base + 2 * len), i3 = pad(base + 3 * len);
      float2 w1 = tw[len + j];
      float2 w2 = tw[2 * len + j];
      float2 w3 = tw[3 * len + j];     // = tw[2*len + (j+len)]
      const float w1r = w1.x, w1i = sign * w1.y;
      const float w2r = w2.x, w2i = sign * w2.y;
      const float w3r = w3.x, w3i = sign * w3.y;
      float x0r = re[i0], x0i = im[i0];
      float x1r = re[i1], x1i = im[i1];
      float x2r = re[i2], x2i = im[i2];
      float x3r = re[i3], x3i = im[i3];
      float t1r = w1r * x1r - w1i * x1i, t1i = w1r * x1i + w1i * x1r;
      float t3r = w1r * x3r - w1i * x3i, t3i = w1r * x3i + w1i * x3r;
      float b0r = x0r + t1r, b0i = x0i + t1i;
      float b1r = x0r - t1r, b1i = x0i - t1i;
      float b2r = x2r + t3r, b2i = x2i + t3i;
      float b3r = x2r - t3r, b3i = x2i - t3i;
      float u2r = w2r * b2r - w2i * b2i, u2i = w2r * b2i + w2i * b2r;
      float u3r = w3r * b3r - w3i * b3i, u3i = w3r * b3i + w3i * b3r;
      re[i0] = b0r + u2r; im[i0] = b0i + u2i;
      re[i2] = b0r - u2r; im[i2] = b0i - u2i;
      re[i1] = b1r + u3r; im[i1] = b1i + u3i;
      re[i3] = b1r - u3r; im[i3] = b1i - u3i;
    }
    __syncthreads();
  }
}

// x (B,L,D) -> xT (B,D,L) so fwd_fft loads are coalesced.
__global__ __launch_bounds__(256) void transpose_x(const float* __restrict__ x,
                                                   float* __restrict__ xT) {
  __shared__ float t[32][33];
  const int b = blockIdx.z;
  const int l0 = blockIdx.x * 32, d0 = blockIdx.y * 32;
  const int c = threadIdx.x & 31, r0 = threadIdx.x >> 5;
#pragma unroll
  for (int i = 0; i < 4; ++i) {
    int r = r0 + i * 8;
    t[r][c] = x[((size_t)b * N + l0 + r) * D + d0 + c];
  }
  __syncthreads();
#pragma unroll
  for (int i = 0; i < 4; ++i) {
    int r = r0 + i * 8;
    xT[((size_t)b * D + d0 + r) * N + l0 + c] = t[c][r];
  }
}

// outT (B,D,N) -> out (B,L,D). Final output: non-temporal stores.
__global__ __launch_bounds__(256) void transpose_out(const float* __restrict__ outT,
                                                     float* __restrict__ out) {
  __shared__ float t[32][33];
  const int b = blockIdx.z;
  const int l0 = blockIdx.x * 32, d0 = blockIdx.y * 32;
  const int c = threadIdx.x & 31, r0 = threadIdx.x >> 5;
#pragma unroll
  for (int i = 0; i < 4; ++i) {
    int r = r0 + i * 8;
    t[r][c] = outT[((size_t)b * D + d0 + r) * N + l0 + c];
  }
  __syncthreads();
#pragma unroll
  for (int i = 0; i < 4; ++i) {
    int r = r0 + i * 8;
    __builtin_nontemporal_store(t[c][r], &out[((size_t)b * N + l0 + r) * D + d0 + c]);
  }
}

// Forward rfft(n=8192) of real length-4096 signals via 4096-pt complex FFT.
// 1024 threads (4 waves/SIMD). Layouts: Ufh[b][f][d] (half2), Vf[f][k].
// Blocks 0..255: x (b,d). 256..271: filters (k).
// 272..303: M->f16 re-layout Mt[pm][eq4][k][kd8:16][el:32][8].
__global__ __launch_bounds__(1024) void fwd_fft(const float* __restrict__ xT,
                                                const float* __restrict__ filt,
                                                const float* __restrict__ Mp,
                                                const float* __restrict__ Mm,
                                                uint32_t* __restrict__ Ufh,
                                                float2* __restrict__ Vf,
                                                _Float16* __restrict__ Mt) {
  __shared__ float re[NPAD];
  __shared__ float im[NPAD];
  __shared__ float2 tw[N];
  const int tid = threadIdx.x;
  const int sig = blockIdx.x;

  if (sig >= B * D + K) {          // ---- M prep path ----
    const int pid = sig - (B * D + K);
    const int k = pid & 15, h = pid >> 4;
    const float* src = (h ? Mm : Mp) + (size_t)k * D * D;
    for (int d0 = 0; d0 < D; d0 += 16) {
      for (int i = tid; i < 16 * D; i += 1024) re[i] = src[(size_t)d0 * D + i];
      __syncthreads();
      if (tid < 256) {
        const int e = tid >> 1, c0 = (tid & 1) * 8;
        f16x8 w;
#pragma unroll
        for (int j = 0; j < 8; ++j) w[j] = (_Float16)re[(c0 + j) * D + e];
        const int eq = e >> 5, el = e & 31;
        const size_t kd8 = (size_t)(d0 + c0) >> 3;
        *(f16x8*)(Mt + (((((size_t)h * 4 + eq) * K + k) * 16 + kd8) * 32 + el) * 8) = w;
      }
      __syncthreads();
    }
    return;
  }

  fill_tw(tw, tid, 1024);

  const float* in; int istride;
  int b = 0, d = 0, k = 0;
  const bool isx = sig < B * D;
  if (isx) { b = sig >> 7; d = sig & (D - 1); in = xT + ((size_t)b * D + d) * N; istride = 1; }
  else     { k = sig - B * D; in = filt + k; istride = K; }

  for (int m = tid; m < N; m += 1024) {
    float vr = 0.f, vi = 0.f;
    if (m < (N >> 1)) {
      if (istride == 1) { float2 z = ((const float2*)in)[m]; vr = z.x; vi = z.y; }
      else { vr = in[(size_t)(2 * m) * istride]; vi = in[(size_t)(2 * m + 1) * istride]; }
    }
    int dst = pad(__brev(m) >> (32 - LOGN));
    re[dst] = vr; im[dst] = vi;
  }
  __syncthreads();
  fft_lds(re, im, tw, tid, 1024, -1.0f);

  // recombine in (f, N-f) pairs sharing one sincos
  for (int f = tid; f <= (N >> 1); f += 1024) {
    int f2 = f & (N - 1), fn = (N - f) & (N - 1);
    float zr = re[pad(f2)], zi = im[pad(f2)];
    float nr = re[pad(fn)], ni = im[pad(fn)];
    float Er = 0.5f * (zr + nr), Ei = 0.5f * (zi - ni);
    float Or = 0.5f * (zi + ni), Oi = -0.5f * (zr - nr);
    float ang = -PI_F * (float)f / (float)N;
    float wi_, wr_; __sincosf(ang, &wi_, &wr_);
    float X0r = Er + wr_ * Or - wi_ * Oi;
    float X0i = Ei + wr_ * Oi + wi_ * Or;
    float X1r = Er - wr_ * Or + wi_ * Oi;
    float X1i = -Ei + wr_ * Oi + wi_ * Or;
    if (isx) {
      uint32_t* o = Ufh + ((size_t)b * F_TOT) * D + d;
      o[(size_t)f * D]       = packh2(X0r, X0i);
      o[(size_t)(N - f) * D] = packh2(X1r, X1i);
    } else {
      Vf[(size_t)f * K + k]       = make_float2(X0r, X0i);
      Vf[(size_t)(N - f) * K + k] = make_float2(X1r, X1i);
    }
  }
}

// MFMA middle — single pass over ALL 16 k per block (A k-invariant in
// registers): single Gt slab. XCD co-location swizzle: 1D grid 544, id%8
// selects the f-slice residue so the 4 eq-blocks sharing one Ufh f-slice
// land on ONE XCD's L2. Block = 32 f x 32 e, 4 waves. Proven step schedule:
// 16 merged 16 KB steps (both pm tiles per k), double-buffer,
// vmcnt(0)+barrier per step. launch_bounds(256,3) — the verified no-spill
// envelope (VGPR 80-92; (256,4) forces a 64-VGPR cap and scratch spill).
__global__ __launch_bounds__(256, 3) void middle_mfma(const uint32_t* __restrict__ Ufh,
                                                      const float2* __restrict__ Vf,
                                                      const _Float16* __restrict__ Mt,
                                                      float2* __restrict__ Gt) {
  __shared__ __align__(16) char smem[8192 + 2 * 16384];   // Vl + 2 x 16KB step tiles
  float2*   Vl   = (float2*)smem;              // [pm2][fl32][k16] = 8 KB
  char*     bbuf = smem + 8192;

  // ---- XCD co-location decode: xcd = id%8 (heuristic), fx8 ≡ id (mod 8)
  const int lin = blockIdx.x;
  const int r8 = lin & 7, m = lin >> 3;        // m in [0,68)
  const int fx8 = (m >> 2) * 8 + r8;           // f-tile index, ≡ r8 (mod 8)
  const int eq  = m & 3;
  if (fx8 > 128) return;
  const int fx = fx8 * 32;

  const int tid = threadIdx.x;
  const int l = tid & 63, w = tid >> 6;
  const int l15 = l & 15, g = l >> 4;
  const int fg = w >> 1, eg = w & 1;
  const int fo = l15 >> 2, bb = (l15 >> 1) & 1, ri = l15 & 1;

  // stage BOTH pm tiles (16 KB) for k-step kk into buffer buf
  auto STAGE = [&](int buf, int kk) {
#pragma unroll
    for (int i = 0; i < 4; ++i) {
      const int oe = w * 2048 + i * 512;       // f16 element offset in [2][4096]
      const int pm = oe >> 12, within = oe & 4095;
      const _Float16* src = Mt + (((size_t)pm * 4 + eq) * K + kk) * 4096 + within + l * 8;
      gload_lds16((const void*)src,
                  (void*)(bbuf + (size_t)buf * 16384 + (size_t)oe * 2));
    }
  };
  STAGE(0, 0);

  // ---- V into LDS: Vl[pm][fl][k], all 16 k
  {
    const int fl = tid >> 3, kq = tid & 7;
    int fe = fx + fl; if (fe > N) fe = N;
    *(float4*)&Vl[((size_t)0 * 32 + fl) * 16 + kq * 2] =
        *(const float4*)&Vf[(size_t)fe * K + kq * 2];
    *(float4*)&Vl[((size_t)1 * 32 + fl) * 16 + kq * 2] =
        *(const float4*)&Vf[(size_t)(N - fe) * K + kq * 2];
  }

  // ---- k-invariant A fragments: A[s][ds], a[j] = U[b, f, d=ds*32+g*8+j].(ri)
  f16x8 A[4][4];
#pragma unroll
  for (int s = 0; s < 4; ++s) {
    int f = fx + fg * 16 + s * 4 + fo; if (f > N) f = N;
    const uint4* ur = (const uint4*)(Ufh + ((size_t)bb * F_TOT + f) * D);
#pragma unroll
    for (int ds = 0; ds < 4; ++ds) {
      uint4 w0 = ur[ds * 8 + g * 2];
      uint4 w1 = ur[ds * 8 + g * 2 + 1];
      f16x8 a;
      a[0] = hpick(w0.x, ri); a[1] = hpick(w0.y, ri);
      a[2] = hpick(w0.z, ri); a[3] = hpick(w0.w, ri);
      a[4] = hpick(w1.x, ri); a[5] = hpick(w1.y, ri);
      a[6] = hpick(w1.z, ri); a[7] = hpick(w1.w, ri);
      A[s][ds] = a;
    }
  }

  f32x4 acc[4];
#pragma unroll
  for (int s = 0; s < 4; ++s) acc[s] = (f32x4)0.f;

  asm volatile("s_waitcnt vmcnt(0)" ::: "memory");
  __syncthreads();

  int buf = 0;
  for (int st = 0; st < K; ++st) {
    if (st < K - 1) STAGE(buf ^ 1, st + 1);
    const _Float16* bc = (const _Float16*)(bbuf + (size_t)buf * 16384);

#pragma unroll
    for (int pm = 0; pm < 2; ++pm) {
      float2 vv[4];
#pragma unroll
      for (int s = 0; s < 4; ++s)
        vv[s] = Vl[((size_t)pm * 32 + fg * 16 + s * 4 + g) * 16 + st];

      f32x4 P[4];
#pragma unroll
      for (int ds = 0; ds < 4; ++ds) {
        f16x8 bf = *(const f16x8*)(bc + (size_t)pm * 4096 +
                                   (size_t)((ds * 4 + g) * 32 + eg * 16 + l15) * 8);
#pragma unroll
        for (int s = 0; s < 4; ++s) {
          f32x4 cin = (ds == 0) ? (f32x4)0.f : P[s];
          P[s] = __builtin_amdgcn_mfma_f32_16x16x32_f16(A[s][ds], bf, cin, 0, 0, 0);
        }
      }
#pragma unroll
      for (int s = 0; s < 4; ++s) {
        const float vr = vv[s].x, vy = vv[s].y;
        if (pm == 0) {   // G += (vr + i vy) * (PR + i PI)
          acc[s][0] += vr * P[s][0] - vy * P[s][1];
          acc[s][1] += vy * P[s][0] + vr * P[s][1];
          acc[s][2] += vr * P[s][2] - vy * P[s][3];
          acc[s][3] += vy * P[s][2] + vr * P[s][3];
        } else {         // G += conj(vr + i vy) * (PR + i PI)
          acc[s][0] += vr * P[s][0] + vy * P[s][1];
          acc[s][1] += vr * P[s][1] - vy * P[s][0];
          acc[s][2] += vr * P[s][2] + vy * P[s][3];
          acc[s][3] += vr * P[s][3] - vy * P[s][2];
        }
      }
    }
    asm volatile("s_waitcnt vmcnt(0)" ::: "memory");
    __syncthreads();
    buf ^= 1;
  }

  // ---- epilogue: LDS transpose (aliases smem) -> coalesced NT float4 stores
  float2* tr = (float2*)smem;   // [64][33]
#pragma unroll
  for (int s = 0; s < 4; ++s) {
    const int fl = fg * 16 + s * 4 + g;
    const int el = eg * 16 + l15;
    tr[(size_t)el * 33 + fl]        = make_float2(acc[s][0], acc[s][1]);
    tr[(size_t)(32 + el) * 33 + fl] = make_float2(acc[s][2], acc[s][3]);
  }
  __syncthreads();
#pragma unroll
  for (int p = 0; p < 4; ++p) {
    const int row = p * 16 + (tid >> 4);        // row = bo*32 + e_local
    const int bo = row >> 5, e_gl = eq * 32 + (row & 31);
    const int c = (tid & 15) * 2;
    const int fgl = fx + c;
    if (fgl < F_TOT) {
      float2 v0 = tr[(size_t)row * 33 + c], v1 = tr[(size_t)row * 33 + c + 1];
      f32x4 v = {v0.x, v0.y, v1.x, v1.y};
      __builtin_nontemporal_store(v, (f32x4*)&Gt[((size_t)bo * D + e_gl) * FP + fgl]);
    }
  }
}

// irfft(n=8192) per (b,e): NON-TEMPORAL coalesced row reads of the single
// Gt slab, (kk, N-kk) pairs share one twiddle, fused-pass FFT, coalesced
// outT writes. 1024 threads.
__global__ __launch_bounds__(1024) void inv_fft(const float2* __restrict__ Gt,
                                                float* __restrict__ outT) {
  __shared__ float re[NPAD];
  __shared__ float im[NPAD];
  __shared__ float2 tw[N];
  const int tid = threadIdx.x;
  const int sig = blockIdx.x;
  const int b = sig >> 7, e = sig & (D - 1);
  const float2* g0 = Gt + ((size_t)b * D + e) * FP;

  fill_tw(tw, tid, 1024);

  for (int kk = tid; kk <= (N >> 1); kk += 1024) {
    float2 Xk = ntload2(&g0[kk]);
    float2 Xn = ntload2(&g0[N - kk]);
    float Er = 0.5f * (Xk.x + Xn.x), Ei = 0.5f * (Xk.y - Xn.y);
    float Dr = 0.5f * (Xk.x - Xn.x), Di = 0.5f * (Xk.y + Xn.y);
    float ang = PI_F * (float)kk / (float)N;
    float wi_, wr_; __sincosf(ang, &wi_, &wr_);
    float Or = Dr * wr_ - Di * wi_;
    float Oi = Dr * wi_ + Di * wr_;
    int d1 = pad(__brev(kk) >> (32 - LOGN));
    re[d1] = Er - Oi; im[d1] = Ei + Or;
    if (kk != 0 && kk != (N >> 1)) {
      int d2 = pad(__brev(N - kk) >> (32 - LOGN));
      re[d2] = Er + Oi; im[d2] = -Ei + Or;   // conj-pair: same twiddle
    }
  }
  __syncthreads();
  fft_lds(re, im, tw, tid, 1024, +1.0f);
  const float scale = 1.0f / (float)N;
  float2* ob = (float2*)(outT + ((size_t)b * D + e) * N);
  for (int m = tid; m < (N >> 1); m += 1024) {
    int i0 = pad(m);
    ob[m] = make_float2(re[i0] * scale, im[i0] * scale);
  }
}

extern "C" void kernel_launch(void* const* d_in, const int* in_sizes, int n_in,
                              void* d_out, int out_size, void* d_ws, size_t ws_size,
                              hipStream_t stream) {
  const float* x  = (const float*)d_in[0];
  const float* fl = (const float*)d_in[1];
  const float* Mp = (const float*)d_in[2];
  const float* Mm = (const float*)d_in[3];
  float* out = (float*)d_out;

  float*    xT  = (float*)d_ws;                               // B*D*N f32 (4 MB), reused as outT
  uint32_t* Ufh = (uint32_t*)(xT + (size_t)B * D * N);        // B*F_TOT*D half2 ([b][f][d])
  float2*   Vf  = (float2*)(Ufh + (size_t)B * F_TOT * D);     // F_TOT*K ([f][k])
  float2*   Gt  = Vf + (size_t)F_TOT * K;                     // single slab B*D*FP
  _Float16* Mt  = (_Float16*)(Gt + (size_t)B * D * FP);       // 1 MB f16

  transpose_x<<<dim3(N / 32, D / 32, B), 256, 0, stream>>>(x, xT);
  fwd_fft<<<B * D + K + 32, 1024, 0, stream>>>(xT, fl, Mp, Mm, Ufh, Vf, Mt);
  middle_mfma<<<544, 256, 0, stream>>>(Ufh, Vf, Mt, Gt);
  inv_fft<<<B * D, 1024, 0, stream>>>(Gt, xT);   // xT reused as outT (B,D,N)
  transpose_out<<<dim3(N / 32, D / 32, B), 256, 0, stream>>>(xT, out);
}